// Round 1
// baseline (21320.943 us; speedup 1.0000x reference)
//
#include <hip/hip_runtime.h>
#include <hip/hip_bf16.h>
#include <cstdint>
#include <cstddef>

// ---------------- block reduction (256 threads = 4 waves) ----------------
__device__ __forceinline__ float block_sum(float v, float* sm) {
    __syncthreads();
    #pragma unroll
    for (int off = 32; off > 0; off >>= 1) v += __shfl_down(v, off, 64);
    int w = threadIdx.x >> 6;
    if ((threadIdx.x & 63) == 0) sm[w] = v;
    __syncthreads();
    return sm[0] + sm[1] + sm[2] + sm[3];
}

// ---------------- LayerNorm: one block per row, E=1024 ----------------
__global__ __launch_bounds__(256) void ln_kernel(const float* __restrict__ x,
                                                 const float* __restrict__ g,
                                                 const float* __restrict__ b,
                                                 float* __restrict__ out) {
    __shared__ float sm[4];
    const int E = 1024;
    size_t row = blockIdx.x;
    const float* xr = x + row * E;
    float v[4];
    float s = 0.f;
    #pragma unroll
    for (int j = 0; j < 4; j++) { v[j] = xr[threadIdx.x + 256*j]; s += v[j]; }
    s = block_sum(s, sm);
    float mean = s * (1.f/1024.f);
    float vs = 0.f;
    #pragma unroll
    for (int j = 0; j < 4; j++) { float d = v[j] - mean; vs += d*d; }
    vs = block_sum(vs, sm);
    float inv = rsqrtf(vs * (1.f/1024.f) + 1e-5f);
    float* orow = out + row * E;
    #pragma unroll
    for (int j = 0; j < 4; j++) {
        int i = threadIdx.x + 256*j;
        orow[i] = (v[j]-mean)*inv*g[i] + b[i];
    }
}

// ---------------- GEMM: C[M,N] = A[M,K] @ W[N,K]^T, fused epilogues ----------
// MODE 0: C = acc (+bias if non-null)
// MODE 1: C = relu(acc)^2
// MODE 2: C += sigmoid(R) * acc      (ChannelMix tail)
// MODE 3: C += acc                   (residual add)
template<int MODE>
__global__ __launch_bounds__(256) void gemm_nt(const float* __restrict__ A,
                                               const float* __restrict__ W,
                                               const float* __restrict__ bias,
                                               const float* __restrict__ R,
                                               float* __restrict__ C,
                                               int M, int N, int K) {
    constexpr int BM = 128, BN = 128, BK = 16;
    __shared__ float As[BK][BM+4];
    __shared__ float Ws[BK][BN+4];
    const int tid = threadIdx.x;
    const int tx = tid & 15, ty = tid >> 4;
    const int m0 = blockIdx.y * BM, n0 = blockIdx.x * BN;
    float acc[8][8] = {};

    for (int k0 = 0; k0 < K; k0 += BK) {
        #pragma unroll
        for (int i = 0; i < 2; i++) {
            int l = tid + 256*i;                 // 0..511
            int row = l >> 2, c4 = (l & 3) * 4;  // 128 rows x 4 float4
            float4 av = *reinterpret_cast<const float4*>(&A[(size_t)(m0+row)*K + k0 + c4]);
            As[c4+0][row] = av.x; As[c4+1][row] = av.y;
            As[c4+2][row] = av.z; As[c4+3][row] = av.w;
        }
        #pragma unroll
        for (int i = 0; i < 2; i++) {
            int l = tid + 256*i;
            int row = l >> 2, c4 = (l & 3) * 4;
            float4 wv = *reinterpret_cast<const float4*>(&W[(size_t)(n0+row)*K + k0 + c4]);
            Ws[c4+0][row] = wv.x; Ws[c4+1][row] = wv.y;
            Ws[c4+2][row] = wv.z; Ws[c4+3][row] = wv.w;
        }
        __syncthreads();
        #pragma unroll
        for (int kk = 0; kk < BK; kk++) {
            float4 a0 = *reinterpret_cast<const float4*>(&As[kk][ty*8]);
            float4 a1 = *reinterpret_cast<const float4*>(&As[kk][ty*8+4]);
            float4 w0 = *reinterpret_cast<const float4*>(&Ws[kk][tx*8]);
            float4 w1 = *reinterpret_cast<const float4*>(&Ws[kk][tx*8+4]);
            float a[8] = {a0.x,a0.y,a0.z,a0.w,a1.x,a1.y,a1.z,a1.w};
            float w[8] = {w0.x,w0.y,w0.z,w0.w,w1.x,w1.y,w1.z,w1.w};
            #pragma unroll
            for (int i = 0; i < 8; i++)
                #pragma unroll
                for (int j = 0; j < 8; j++)
                    acc[i][j] = fmaf(a[i], w[j], acc[i][j]);
        }
        __syncthreads();
    }

    #pragma unroll
    for (int i = 0; i < 8; i++) {
        size_t m = (size_t)(m0 + ty*8 + i);
        size_t off = m * N + n0 + tx*8;
        #pragma unroll
        for (int j4 = 0; j4 < 2; j4++) {
            float4 v;
            v.x = acc[i][j4*4+0]; v.y = acc[i][j4*4+1];
            v.z = acc[i][j4*4+2]; v.w = acc[i][j4*4+3];
            if (MODE == 0) {
                if (bias) {
                    float4 bv = *reinterpret_cast<const float4*>(&bias[n0 + tx*8 + j4*4]);
                    v.x += bv.x; v.y += bv.y; v.z += bv.z; v.w += bv.w;
                }
                *reinterpret_cast<float4*>(&C[off + j4*4]) = v;
            } else if (MODE == 1) {
                v.x = fmaxf(v.x, 0.f); v.x *= v.x;
                v.y = fmaxf(v.y, 0.f); v.y *= v.y;
                v.z = fmaxf(v.z, 0.f); v.z *= v.z;
                v.w = fmaxf(v.w, 0.f); v.w *= v.w;
                *reinterpret_cast<float4*>(&C[off + j4*4]) = v;
            } else if (MODE == 2) {
                float4 c = *reinterpret_cast<const float4*>(&C[off + j4*4]);
                float4 r = *reinterpret_cast<const float4*>(&R[off + j4*4]);
                c.x += v.x / (1.f + expf(-r.x));
                c.y += v.y / (1.f + expf(-r.y));
                c.z += v.z / (1.f + expf(-r.z));
                c.w += v.w / (1.f + expf(-r.w));
                *reinterpret_cast<float4*>(&C[off + j4*4]) = c;
            } else {
                float4 c = *reinterpret_cast<const float4*>(&C[off + j4*4]);
                c.x += v.x; c.y += v.y; c.z += v.z; c.w += v.w;
                *reinterpret_cast<float4*>(&C[off + j4*4]) = c;
            }
        }
    }
}

// ---------------- WKV recurrence: one thread per (b,e) channel -------------
// v == r in this model; sigmoid(r)*wkv is folded into the y write.
__global__ __launch_bounds__(64) void wkv_kernel(const float* __restrict__ k,
                                                 const float* __restrict__ v,
                                                 const float* __restrict__ decay,
                                                 const float* __restrict__ first,
                                                 float* __restrict__ y) {
    const int T = 1024, E = 1024;
    int idx = blockIdx.x * 64 + threadIdx.x;   // 0..4095 = B*E
    int b = idx >> 10, e = idx & 1023;
    float w = -expf(decay[e]);
    float u = first[e];
    float aa = 0.f, bb = 0.f, pp = -1e38f;
    const float* kp = k + (size_t)b*T*E + e;
    const float* vp = v + (size_t)b*T*E + e;
    float* yp = y + (size_t)b*T*E + e;
    float kt = kp[0], vt = vp[0];
    for (int t = 0; t < T; t++) {
        float kn = 0.f, vn = 0.f;
        if (t + 1 < T) { kn = kp[(size_t)(t+1)*E]; vn = vp[(size_t)(t+1)*E]; }
        float ww = u + kt;
        float p  = fmaxf(pp, ww);
        float e1 = expf(pp - p), e2 = expf(ww - p);
        float yt = (e1*aa + e2*vt) / (e1*bb + e2);
        yp[(size_t)t*E] = yt / (1.f + expf(-vt));   // sigmoid(r) * wkv
        float ww2 = pp + w;
        float p2  = fmaxf(ww2, kt);
        float e1b = expf(ww2 - p2), e2b = expf(kt - p2);
        aa = fmaf(e1b, aa, e2b*vt);
        bb = fmaf(e1b, bb, e2b);
        pp = p2;
        kt = kn; vt = vn;
    }
}

extern "C" void kernel_launch(void* const* d_in, const int* in_sizes, int n_in,
                              void* d_out, int out_size, void* d_ws, size_t ws_size,
                              hipStream_t stream) {
    const float* inputs   = (const float*)d_in[0];
    const float* W_in     = (const float*)d_in[1];
    const float* b_in     = (const float*)d_in[2];
    const float* l0_ln0_g = (const float*)d_in[3];
    const float* l0_ln0_b = (const float*)d_in[4];
    const float* l0_ln1_g = (const float*)d_in[5];
    const float* l0_ln1_b = (const float*)d_in[6];
    const float* l0_ln2_g = (const float*)d_in[7];
    const float* l0_ln2_b = (const float*)d_in[8];
    const float* l0_cm_k  = (const float*)d_in[9];
    const float* l0_cm_v  = (const float*)d_in[10];
    const float* l0_cm_r  = (const float*)d_in[11];
    const float* l0_ff_k  = (const float*)d_in[12];
    const float* l0_ff_v  = (const float*)d_in[13];
    const float* l0_ff_r  = (const float*)d_in[14];
    const float* tm_k     = (const float*)d_in[15];
    const float* tm_r     = (const float*)d_in[16];
    const float* tm_o     = (const float*)d_in[17];
    const float* tm_decay = (const float*)d_in[18];
    const float* tm_first = (const float*)d_in[19];
    const float* ln1_g    = (const float*)d_in[20];
    const float* ln1_b    = (const float*)d_in[21];
    const float* ln2_g    = (const float*)d_in[22];
    const float* ln2_b    = (const float*)d_in[23];
    const float* ff_k     = (const float*)d_in[24];
    const float* ff_v     = (const float*)d_in[25];
    const float* ff_r     = (const float*)d_in[26];
    const float* out_g    = (const float*)d_in[27];
    const float* out_b    = (const float*)d_in[28];

    const int Mrows = 4096, E = 1024, E4 = 4096, D = 512, L1 = 11;
    float* ws = (float*)d_ws;
    const size_t S = (size_t)Mrows * E;
    float* res = ws;          // [M,E]
    float* xn  = ws + 1*S;    // [M,E]
    float* kb  = ws + 2*S;    // [M,E]
    float* rb  = ws + 3*S;    // [M,E]
    float* yb  = ws + 4*S;    // [M,E]
    float* hb  = ws + 5*S;    // [M,4E]  (4*S floats)
    (void)ws_size; (void)in_sizes; (void)n_in; (void)out_size;

    dim3 blk(256);
    dim3 gE (E /128, Mrows/128);   // (8,32)
    dim3 gE4(E4/128, Mrows/128);   // (32,32)

    // x = inputs @ W_in.T + b_in  -> kb
    gemm_nt<0><<<gE, blk, 0, stream>>>(inputs, W_in, b_in, nullptr, kb, Mrows, E, D);
    // res = LN(x, ln0)
    ln_kernel<<<Mrows, blk, 0, stream>>>(kb, l0_ln0_g, l0_ln0_b, res);
    // res += CM(LN(res, ln1); cm_k, cm_v, cm_r)
    ln_kernel<<<Mrows, blk, 0, stream>>>(res, l0_ln1_g, l0_ln1_b, xn);
    gemm_nt<1><<<gE4, blk, 0, stream>>>(xn, l0_cm_k, nullptr, nullptr, hb, Mrows, E4, E);
    gemm_nt<0><<<gE,  blk, 0, stream>>>(xn, l0_cm_r, nullptr, nullptr, rb, Mrows, E, E);
    gemm_nt<2><<<gE,  blk, 0, stream>>>(hb, l0_cm_v, nullptr, rb, res, Mrows, E, E4);
    // res += CM(LN(res, ln2); ff_k, ff_v, ff_r)   [layer-0 ffn]
    ln_kernel<<<Mrows, blk, 0, stream>>>(res, l0_ln2_g, l0_ln2_b, xn);
    gemm_nt<1><<<gE4, blk, 0, stream>>>(xn, l0_ff_k, nullptr, nullptr, hb, Mrows, E4, E);
    gemm_nt<0><<<gE,  blk, 0, stream>>>(xn, l0_ff_r, nullptr, nullptr, rb, Mrows, E, E);
    gemm_nt<2><<<gE,  blk, 0, stream>>>(hb, l0_ff_v, nullptr, rb, res, Mrows, E, E4);

    for (int l = 0; l < L1; l++) {
        const float* Wk = tm_k + (size_t)l*E*E;
        const float* Wr = tm_r + (size_t)l*E*E;
        const float* Wo = tm_o + (size_t)l*E*E;
        // xn = LN(res, ln1[l])
        ln_kernel<<<Mrows, blk, 0, stream>>>(res, ln1_g + (size_t)l*E, ln1_b + (size_t)l*E, xn);
        // k = xn @ Wk.T ; r = xn @ Wr.T
        gemm_nt<0><<<gE, blk, 0, stream>>>(xn, Wk, nullptr, nullptr, kb, Mrows, E, E);
        gemm_nt<0><<<gE, blk, 0, stream>>>(xn, Wr, nullptr, nullptr, rb, Mrows, E, E);
        // y = sigmoid(r) * wkv(-exp(decay), first, k, r)
        wkv_kernel<<<64, 64, 0, stream>>>(kb, rb, tm_decay + (size_t)l*E, tm_first + (size_t)l*E, yb);
        // res += y @ Wo.T
        gemm_nt<3><<<gE, blk, 0, stream>>>(yb, Wo, nullptr, nullptr, res, Mrows, E, E);
        // res += CM(LN(res, ln2[l]); ff_k[l], ff_v[l], ff_r[l])
        ln_kernel<<<Mrows, blk, 0, stream>>>(res, ln2_g + (size_t)l*E, ln2_b + (size_t)l*E, xn);
        gemm_nt<1><<<gE4, blk, 0, stream>>>(xn, ff_k + (size_t)l*E4*E, nullptr, nullptr, hb, Mrows, E4, E);
        gemm_nt<0><<<gE,  blk, 0, stream>>>(xn, ff_r + (size_t)l*E*E,  nullptr, nullptr, rb, Mrows, E, E);
        gemm_nt<2><<<gE,  blk, 0, stream>>>(hb, ff_v + (size_t)l*E*E4, nullptr, rb, res, Mrows, E, E4);
    }

    // out = LN(res, out_g, out_b)
    ln_kernel<<<Mrows, blk, 0, stream>>>(res, out_g, out_b, (float*)d_out);
}

// Round 2
// 10505.900 us; speedup vs baseline: 2.0294x; 2.0294x over previous
//
#include <hip/hip_runtime.h>
#include <hip/hip_bf16.h>
#include <cstdint>
#include <cstddef>

typedef __attribute__((ext_vector_type(8))) __bf16 bf16x8;
typedef __attribute__((ext_vector_type(4))) float f32x4;

__device__ __forceinline__ unsigned cvt_pk(float x, float y) {
    __hip_bfloat162 h = __float22bfloat162_rn(make_float2(x, y));
    return *reinterpret_cast<unsigned*>(&h);
}

// ---------------- block reduction (256 threads = 4 waves) ----------------
__device__ __forceinline__ float block_sum(float v, float* sm) {
    __syncthreads();
    #pragma unroll
    for (int off = 32; off > 0; off >>= 1) v += __shfl_down(v, off, 64);
    int w = threadIdx.x >> 6;
    if ((threadIdx.x & 63) == 0) sm[w] = v;
    __syncthreads();
    return sm[0] + sm[1] + sm[2] + sm[3];
}

// ---------------- LayerNorm: one block per row, E=1024 ----------------
__global__ __launch_bounds__(256) void ln_kernel(const float* __restrict__ x,
                                                 const float* __restrict__ g,
                                                 const float* __restrict__ b,
                                                 float* __restrict__ out) {
    __shared__ float sm[4];
    const int E = 1024;
    size_t row = blockIdx.x;
    const float* xr = x + row * E;
    float v[4];
    float s = 0.f;
    #pragma unroll
    for (int j = 0; j < 4; j++) { v[j] = xr[threadIdx.x + 256*j]; s += v[j]; }
    s = block_sum(s, sm);
    float mean = s * (1.f/1024.f);
    float vs = 0.f;
    #pragma unroll
    for (int j = 0; j < 4; j++) { float d = v[j] - mean; vs += d*d; }
    vs = block_sum(vs, sm);
    float inv = rsqrtf(vs * (1.f/1024.f) + 1e-5f);
    float* orow = out + row * E;
    #pragma unroll
    for (int j = 0; j < 4; j++) {
        int i = threadIdx.x + 256*j;
        orow[i] = (v[j]-mean)*inv*g[i] + b[i];
    }
}

// ---------------- MFMA GEMM: C[M,N] = A[M,K] @ W[N,K]^T ------------------
// fp32 global operands, converted to bf16 during LDS staging; fp32 accumulate.
// MODE 0: C = acc (+bias if non-null)
// MODE 1: C = relu(acc)^2
// MODE 2: C += sigmoid(R) * acc      (ChannelMix tail)
// MODE 3: C += acc                   (residual add)
template<int MODE>
__global__ __launch_bounds__(256) void gemm_nt(const float* __restrict__ A,
                                               const float* __restrict__ W,
                                               const float* __restrict__ bias,
                                               const float* __restrict__ R,
                                               float* __restrict__ C,
                                               int M, int N, int K) {
    constexpr int BM = 128, BN = 128, BK = 32;
    constexpr int PAD = 40;                       // LDS row stride in bf16 elems
    __shared__ unsigned short As[BM * PAD];       // 10240 B
    __shared__ unsigned short Ws[BN * PAD];       // 10240 B
    const int tid  = threadIdx.x;
    const int wave = tid >> 6, lane = tid & 63;
    const int waveM = wave >> 1, waveN = wave & 1;     // 2x2 wave grid
    const int r16 = lane & 15, quad = lane >> 4;
    const int m0 = blockIdx.y * BM, n0 = blockIdx.x * BN;

    f32x4 acc[4][4] = {};   // [mt][nt], 64 VGPR/AGPR

    for (int k0 = 0; k0 < K; k0 += BK) {
        // ---- stage A tile: 128 rows x 32 fp32 -> bf16 LDS ----
        #pragma unroll
        for (int i = 0; i < 4; i++) {
            int f = i * 256 + tid;            // 0..1023 float4 chunks
            int row = f >> 3, c4 = f & 7;     // 8 float4 per row
            float4 av = *reinterpret_cast<const float4*>(&A[(size_t)(m0 + row) * K + k0 + c4 * 4]);
            unsigned lo = cvt_pk(av.x, av.y), hi = cvt_pk(av.z, av.w);
            *reinterpret_cast<uint2*>(&As[row * PAD + c4 * 4]) = make_uint2(lo, hi);
        }
        // ---- stage W tile ----
        #pragma unroll
        for (int i = 0; i < 4; i++) {
            int f = i * 256 + tid;
            int row = f >> 3, c4 = f & 7;
            float4 wv = *reinterpret_cast<const float4*>(&W[(size_t)(n0 + row) * K + k0 + c4 * 4]);
            unsigned lo = cvt_pk(wv.x, wv.y), hi = cvt_pk(wv.z, wv.w);
            *reinterpret_cast<uint2*>(&Ws[row * PAD + c4 * 4]) = make_uint2(lo, hi);
        }
        __syncthreads();

        // ---- fragments: A[m=lane&15][k=quad*8+j], B[n=lane&15][k=quad*8+j] ----
        bf16x8 af[4], bfr[4];
        #pragma unroll
        for (int mt = 0; mt < 4; mt++)
            af[mt] = *reinterpret_cast<const bf16x8*>(&As[(waveM * 64 + mt * 16 + r16) * PAD + quad * 8]);
        #pragma unroll
        for (int nt = 0; nt < 4; nt++)
            bfr[nt] = *reinterpret_cast<const bf16x8*>(&Ws[(waveN * 64 + nt * 16 + r16) * PAD + quad * 8]);

        #pragma unroll
        for (int mt = 0; mt < 4; mt++)
            #pragma unroll
            for (int nt = 0; nt < 4; nt++)
                acc[mt][nt] = __builtin_amdgcn_mfma_f32_16x16x32_bf16(af[mt], bfr[nt], acc[mt][nt], 0, 0, 0);
        __syncthreads();
    }

    // ---- epilogue: D[row=quad*4+r][col=lane&15] ----
    #pragma unroll
    for (int mt = 0; mt < 4; mt++) {
        #pragma unroll
        for (int r = 0; r < 4; r++) {
            int m = m0 + waveM * 64 + mt * 16 + quad * 4 + r;
            #pragma unroll
            for (int nt = 0; nt < 4; nt++) {
                int n = n0 + waveN * 64 + nt * 16 + r16;
                size_t off = (size_t)m * N + n;
                float v = acc[mt][nt][r];
                if (MODE == 0) {
                    if (bias) v += bias[n];
                    C[off] = v;
                } else if (MODE == 1) {
                    v = fmaxf(v, 0.f);
                    C[off] = v * v;
                } else if (MODE == 2) {
                    C[off] += v / (1.f + expf(-R[off]));
                } else {
                    C[off] += v;
                }
            }
        }
    }
}

// ---------------- WKV recurrence: one thread per (b,e) channel -------------
// v == r in this model; sigmoid(r)*wkv is folded into the y write.
__global__ __launch_bounds__(64) void wkv_kernel(const float* __restrict__ k,
                                                 const float* __restrict__ v,
                                                 const float* __restrict__ decay,
                                                 const float* __restrict__ first,
                                                 float* __restrict__ y) {
    const int T = 1024, E = 1024;
    int idx = blockIdx.x * 64 + threadIdx.x;   // 0..4095 = B*E
    int b = idx >> 10, e = idx & 1023;
    float w = -expf(decay[e]);
    float u = first[e];
    float aa = 0.f, bb = 0.f, pp = -1e38f;
    const float* kp = k + (size_t)b*T*E + e;
    const float* vp = v + (size_t)b*T*E + e;
    float* yp = y + (size_t)b*T*E + e;
    float kt = kp[0], vt = vp[0];
    for (int t = 0; t < T; t++) {
        float kn = 0.f, vn = 0.f;
        if (t + 1 < T) { kn = kp[(size_t)(t+1)*E]; vn = vp[(size_t)(t+1)*E]; }
        float ww = u + kt;
        float p  = fmaxf(pp, ww);
        float e1 = expf(pp - p), e2 = expf(ww - p);
        float yt = (e1*aa + e2*vt) / (e1*bb + e2);
        yp[(size_t)t*E] = yt / (1.f + expf(-vt));   // sigmoid(r) * wkv
        float ww2 = pp + w;
        float p2  = fmaxf(ww2, kt);
        float e1b = expf(ww2 - p2), e2b = expf(kt - p2);
        aa = fmaf(e1b, aa, e2b*vt);
        bb = fmaf(e1b, bb, e2b);
        pp = p2;
        kt = kn; vt = vn;
    }
}

extern "C" void kernel_launch(void* const* d_in, const int* in_sizes, int n_in,
                              void* d_out, int out_size, void* d_ws, size_t ws_size,
                              hipStream_t stream) {
    const float* inputs   = (const float*)d_in[0];
    const float* W_in     = (const float*)d_in[1];
    const float* b_in     = (const float*)d_in[2];
    const float* l0_ln0_g = (const float*)d_in[3];
    const float* l0_ln0_b = (const float*)d_in[4];
    const float* l0_ln1_g = (const float*)d_in[5];
    const float* l0_ln1_b = (const float*)d_in[6];
    const float* l0_ln2_g = (const float*)d_in[7];
    const float* l0_ln2_b = (const float*)d_in[8];
    const float* l0_cm_k  = (const float*)d_in[9];
    const float* l0_cm_v  = (const float*)d_in[10];
    const float* l0_cm_r  = (const float*)d_in[11];
    const float* l0_ff_k  = (const float*)d_in[12];
    const float* l0_ff_v  = (const float*)d_in[13];
    const float* l0_ff_r  = (const float*)d_in[14];
    const float* tm_k     = (const float*)d_in[15];
    const float* tm_r     = (const float*)d_in[16];
    const float* tm_o     = (const float*)d_in[17];
    const float* tm_decay = (const float*)d_in[18];
    const float* tm_first = (const float*)d_in[19];
    const float* ln1_g    = (const float*)d_in[20];
    const float* ln1_b    = (const float*)d_in[21];
    const float* ln2_g    = (const float*)d_in[22];
    const float* ln2_b    = (const float*)d_in[23];
    const float* ff_k     = (const float*)d_in[24];
    const float* ff_v     = (const float*)d_in[25];
    const float* ff_r     = (const float*)d_in[26];
    const float* out_g    = (const float*)d_in[27];
    const float* out_b    = (const float*)d_in[28];

    const int Mrows = 4096, E = 1024, E4 = 4096, D = 512, L1 = 11;
    float* ws = (float*)d_ws;
    const size_t S = (size_t)Mrows * E;
    float* res = ws;          // [M,E]
    float* xn  = ws + 1*S;    // [M,E]
    float* kb  = ws + 2*S;    // [M,E]
    float* rb  = ws + 3*S;    // [M,E]
    float* yb  = ws + 4*S;    // [M,E]
    float* hb  = ws + 5*S;    // [M,4E]  (4*S floats)
    (void)ws_size; (void)in_sizes; (void)n_in; (void)out_size;

    dim3 blk(256);
    dim3 gE (E /128, Mrows/128);   // (8,32)
    dim3 gE4(E4/128, Mrows/128);   // (32,32)

    // x = inputs @ W_in.T + b_in  -> kb
    gemm_nt<0><<<gE, blk, 0, stream>>>(inputs, W_in, b_in, nullptr, kb, Mrows, E, D);
    // res = LN(x, ln0)
    ln_kernel<<<Mrows, blk, 0, stream>>>(kb, l0_ln0_g, l0_ln0_b, res);
    // res += CM(LN(res, ln1); cm_k, cm_v, cm_r)
    ln_kernel<<<Mrows, blk, 0, stream>>>(res, l0_ln1_g, l0_ln1_b, xn);
    gemm_nt<1><<<gE4, blk, 0, stream>>>(xn, l0_cm_k, nullptr, nullptr, hb, Mrows, E4, E);
    gemm_nt<0><<<gE,  blk, 0, stream>>>(xn, l0_cm_r, nullptr, nullptr, rb, Mrows, E, E);
    gemm_nt<2><<<gE,  blk, 0, stream>>>(hb, l0_cm_v, nullptr, rb, res, Mrows, E, E4);
    // res += CM(LN(res, ln2); ff_k, ff_v, ff_r)   [layer-0 ffn]
    ln_kernel<<<Mrows, blk, 0, stream>>>(res, l0_ln2_g, l0_ln2_b, xn);
    gemm_nt<1><<<gE4, blk, 0, stream>>>(xn, l0_ff_k, nullptr, nullptr, hb, Mrows, E4, E);
    gemm_nt<0><<<gE,  blk, 0, stream>>>(xn, l0_ff_r, nullptr, nullptr, rb, Mrows, E, E);
    gemm_nt<2><<<gE,  blk, 0, stream>>>(hb, l0_ff_v, nullptr, rb, res, Mrows, E, E4);

    for (int l = 0; l < L1; l++) {
        const float* Wk = tm_k + (size_t)l*E*E;
        const float* Wr = tm_r + (size_t)l*E*E;
        const float* Wo = tm_o + (size_t)l*E*E;
        // xn = LN(res, ln1[l])
        ln_kernel<<<Mrows, blk, 0, stream>>>(res, ln1_g + (size_t)l*E, ln1_b + (size_t)l*E, xn);
        // k = xn @ Wk.T ; r = xn @ Wr.T
        gemm_nt<0><<<gE, blk, 0, stream>>>(xn, Wk, nullptr, nullptr, kb, Mrows, E, E);
        gemm_nt<0><<<gE, blk, 0, stream>>>(xn, Wr, nullptr, nullptr, rb, Mrows, E, E);
        // y = sigmoid(r) * wkv(-exp(decay), first, k, r)
        wkv_kernel<<<64, 64, 0, stream>>>(kb, rb, tm_decay + (size_t)l*E, tm_first + (size_t)l*E, yb);
        // res += y @ Wo.T
        gemm_nt<3><<<gE, blk, 0, stream>>>(yb, Wo, nullptr, nullptr, res, Mrows, E, E);
        // res += CM(LN(res, ln2[l]); ff_k[l], ff_v[l], ff_r[l])
        ln_kernel<<<Mrows, blk, 0, stream>>>(res, ln2_g + (size_t)l*E, ln2_b + (size_t)l*E, xn);
        gemm_nt<1><<<gE4, blk, 0, stream>>>(xn, ff_k + (size_t)l*E4*E, nullptr, nullptr, hb, Mrows, E4, E);
        gemm_nt<0><<<gE,  blk, 0, stream>>>(xn, ff_r + (size_t)l*E*E,  nullptr, nullptr, rb, Mrows, E, E);
        gemm_nt<2><<<gE,  blk, 0, stream>>>(hb, ff_v + (size_t)l*E*E4, nullptr, rb, res, Mrows, E, E4);
    }

    // out = LN(res, out_g, out_b)
    ln_kernel<<<Mrows, blk, 0, stream>>>(res, out_g, out_b, (float*)d_out);
}